// Round 14
// baseline (204.251 us; speedup 1.0000x reference)
//
#include <hip/hip_runtime.h>

#define NB 32768
#define NCH 8
#define RPW 16  // rows per wave; 2048 single-wave blocks; 16KB private LDS each

typedef __bf16 bf16x8 __attribute__((ext_vector_type(8)));
typedef float f32x4 __attribute__((ext_vector_type(4)));
typedef unsigned int u32;
typedef unsigned short u16;
typedef u32 u32x4v __attribute__((ext_vector_type(4)));

// bf16 weights, transposed to [n][k]. Order: 0=Wi 1=Wf 2=Wo 3=Wu 4=Ui 5=Uf 6=Uo 7=Uu
__device__ __align__(16) u16 g_wt[8 * 128 * 128];

__device__ __forceinline__ u16 f2bf(float f) {
  u32 u = __builtin_bit_cast(u32, f);
  u32 r = u + 0x7FFFu + ((u >> 16) & 1u);  // RNE
  return (u16)(r >> 16);
}
__device__ __forceinline__ float sigm(float s) {
  return __builtin_amdgcn_rcpf(1.0f + __expf(-s));
}
__device__ __forceinline__ float tanh_f(float v) {
  float e = __expf(2.0f * v);
  return 1.0f - 2.0f * __builtin_amdgcn_rcpf(e + 1.0f);
}

__global__ void prep_weights(const float* __restrict__ Wi, const float* __restrict__ Wf,
                             const float* __restrict__ Wo, const float* __restrict__ Wu,
                             const float* __restrict__ Ui, const float* __restrict__ Uf,
                             const float* __restrict__ Uo, const float* __restrict__ Uu) {
  __shared__ float t[128][129];
  const float* srcs[8] = {Wi, Wf, Wo, Wu, Ui, Uf, Uo, Uu};
  const float* s = srcs[blockIdx.x];
  for (int i = threadIdx.x; i < 16384; i += 256) t[i >> 7][i & 127] = s[i];
  __syncthreads();
  u16* dst = g_wt + blockIdx.x * 16384;
  for (int i = threadIdx.x; i < 16384; i += 256) {
    int n = i >> 7, k = i & 127;
    dst[i] = f2bf(t[k][n]);
  }
}

// B-fragment from global bf16 Wt[n][k]: col = lane&15, k = (lane>>4)*8 + e
__device__ __forceinline__ bf16x8 ldB(const u16* wt, int col, int ks, int g) {
  return __builtin_bit_cast(bf16x8, *(const u32x4v*)(wt + col * 128 + ks * 32 + g * 8));
}
// A-fragment from f32 row-swizzled private tile, cvt bf16 on read
__device__ __forceinline__ bf16x8 ldAf(const float* buf, int row, int ks, int g) {
  int s = row & 7;
  const float* base = buf + row * 128 + ks * 32;
  f32x4 lo = *(const f32x4*)(base + (((g * 2) ^ s) << 2));
  f32x4 hi = *(const f32x4*)(base + (((g * 2 + 1) ^ s) << 2));
  bf16x8 r;
  r[0] = (__bf16)lo[0]; r[1] = (__bf16)lo[1]; r[2] = (__bf16)lo[2]; r[3] = (__bf16)lo[3];
  r[4] = (__bf16)hi[0]; r[5] = (__bf16)hi[1]; r[6] = (__bf16)hi[2]; r[7] = (__bf16)hi[3];
  return r;
}

// issue a 16x128 f32 tile into regs: 8 instrs x 1KB contiguous
__device__ __forceinline__ void issue8(const float* __restrict__ src, int lane, f32x4 v[8]) {
#pragma unroll
  for (int i = 0; i < 8; ++i) {
    int row = (lane >> 5) + 2 * i;
    v[i] = *(const f32x4*)(src + row * 128 + (lane & 31) * 4);
  }
}
// commit to row-swizzled layout (ldAf-compatible); optional h_tilde accumulate
template <bool ACC>
__device__ __forceinline__ void commit_h(float* dst, int lane, const f32x4 v[8],
                                         f32x4* hta) {
  int c4 = lane & 31;
#pragma unroll
  for (int i = 0; i < 8; ++i) {
    int row = (lane >> 5) + 2 * i;
    if (ACC) hta[i] += v[i];
    *(f32x4*)(dst + row * 128 + ((c4 ^ (row & 7)) << 2)) = v[i];
  }
}
// commit C with col-swizzle: frag readback dword = col ^ (g<<4), 2-way banked
__device__ __forceinline__ void commit_c(float* dst, int lane, const f32x4 v[8]) {
  int c4 = lane & 31;
#pragma unroll
  for (int i = 0; i < 8; ++i) {
    int row = (lane >> 5) + 2 * i;
    *(f32x4*)(dst + row * 128 + ((c4 ^ (((row >> 2) & 3) << 2)) << 2)) = v[i];
  }
}

// acc[8] += A(16x128 f32 tile) @ B(full 128 cols of Wt); 32 MFMA
__device__ __forceinline__ void gemm_f(const float* a, const u16* wt, int cl, int g,
                                       f32x4 acc[8]) {
#pragma unroll
  for (int ks = 0; ks < 4; ++ks) {
    bf16x8 a0 = ldAf(a, cl, ks, g);
#pragma unroll
    for (int cf = 0; cf < 8; ++cf) {
      bf16x8 b = ldB(wt, cf * 16 + cl, ks, g);
      acc[cf] = __builtin_amdgcn_mfma_f32_16x16x32_bf16(a0, b, acc[cf], 0, 0, 0);
    }
  }
}

// fex swizzle for end-only frag->staging exchange (rows 0..15)
__device__ __forceinline__ int fxsw(int row, int dw) {
  int k = (row >> 2) & 3;
  return row * 128 + (dw ^ (((k & 1) << 4) | ((k >> 1) << 2)));
}

// compute one child from private LDS: f-GEMM + fused f-gate epilogue
__device__ __forceinline__ void child_compute(const float* hbuf, const float* cbuf,
                                              const f32x4 afx[8], const float bfF[8],
                                              int cl, int g, f32x4 fca[8]) {
  f32x4 f[8];
#pragma unroll
  for (int cf = 0; cf < 8; ++cf) f[cf] = afx[cf];
  gemm_f(hbuf, g_wt + 5 * 16384, cl, g, f);
#pragma unroll
  for (int cf = 0; cf < 8; ++cf) {
    int lc = (cf * 16 + cl) ^ (g << 4);
#pragma unroll
    for (int r = 0; r < 4; ++r) {
      float cval = cbuf[(g * 4 + r) * 128 + lc];
      fca[cf][r] += sigm(f[cf][r] + bfF[cf]) * cval;
    }
  }
}

__global__ __launch_bounds__(64) void tree_lstm(
    const float* __restrict__ x, const float* __restrict__ h, const float* __restrict__ C,
    const float* __restrict__ b_i, const float* __restrict__ b_f,
    const float* __restrict__ b_o, const float* __restrict__ b_u,
    float* __restrict__ out) {
  __shared__ float hbuf[RPW * 128];  // 8KB, wave-private (1 wave/block)
  __shared__ float cbuf[RPW * 128];  // 8KB

  const int lane = threadIdx.x;
  const int g = lane >> 4;
  const int cl = lane & 15;
  const int row0 = blockIdx.x * RPW;
  const int c4 = lane & 31;
  const f32x4 fz = {0.f, 0.f, 0.f, 0.f};

  // ---- prologue: x -> cbuf (row-swz); child-0 loads fly under afx GEMM ----
  f32x4 xv[8];
  issue8(x + (size_t)row0 * 128, lane, xv);
  float bfF[8];
#pragma unroll
  for (int cf = 0; cf < 8; ++cf) bfF[cf] = b_f[cf * 16 + cl];
  commit_h<false>(cbuf, lane, xv, nullptr);

  f32x4 hv[8], cv[8];
  issue8(h + (size_t)row0 * 128, lane, hv);
  issue8(C + (size_t)row0 * 128, lane, cv);
  __builtin_amdgcn_sched_barrier(0);

  f32x4 afx[8];
#pragma unroll
  for (int cf = 0; cf < 8; ++cf) afx[cf] = fz;
  gemm_f(cbuf, g_wt + 1 * 16384, cl, g, afx);  // x @ Wf

  f32x4 fca[8], htacc[8];
#pragma unroll
  for (int cf = 0; cf < 8; ++cf) { fca[cf] = fz; htacc[cf] = fz; }

  commit_h<true>(hbuf, lane, hv, htacc);  // child 0 -> LDS
  commit_c(cbuf, lane, cv);               // overwrites x AFTER afx reads (in-order)

  // ---- child loop: no barriers; single buffer; aliasing enforces order ----
#pragma unroll 1
  for (int n = 0; n < NCH - 1; ++n) {
    issue8(h + ((size_t)(n + 1) * NB + row0) * 128, lane, hv);
    issue8(C + ((size_t)(n + 1) * NB + row0) * 128, lane, cv);
    __builtin_amdgcn_sched_barrier(0);  // pin load issue above the compute

    child_compute(hbuf, cbuf, afx, bfF, cl, g, fca);  // child n from LDS

    commit_h<true>(hbuf, lane, hv, htacc);  // child n+1 (waits its own vmcnt)
    commit_c(cbuf, lane, cv);
  }

  // ---- peeled child 7; x reload flies under it ----
  issue8(x + (size_t)row0 * 128, lane, xv);
  __builtin_amdgcn_sched_barrier(0);
  child_compute(hbuf, cbuf, afx, bfF, cl, g, fca);
  commit_h<false>(cbuf, lane, xv, nullptr);     // x -> cbuf
  commit_h<false>(hbuf, lane, htacc, nullptr);  // h_tilde (f32) -> hbuf

  // ---- gates: pre = x@W + h_tilde@U (64 MFMA each) ----
  f32x4 pu[8], pi[8], po[8];
#pragma unroll
  for (int cf = 0; cf < 8; ++cf) { pu[cf] = fz; pi[cf] = fz; po[cf] = fz; }
  gemm_f(cbuf, g_wt + 3 * 16384, cl, g, pu);
  gemm_f(hbuf, g_wt + 7 * 16384, cl, g, pu);
  gemm_f(cbuf, g_wt + 0 * 16384, cl, g, pi);
  gemm_f(hbuf, g_wt + 4 * 16384, cl, g, pi);
  gemm_f(cbuf, g_wt + 2 * 16384, cl, g, po);
  gemm_f(hbuf, g_wt + 6 * 16384, cl, g, po);

  float biF[8], boF[8], buF[8];
#pragma unroll
  for (int cf = 0; cf < 8; ++cf) {
    biF[cf] = b_i[cf * 16 + cl];
    boF[cf] = b_o[cf * 16 + cl];
    buF[cf] = b_u[cf * 16 + cl];
  }

  // elementwise + frag-scatter into the (now free) private tiles
#pragma unroll
  for (int cf = 0; cf < 8; ++cf) {
    int col = cf * 16 + cl;
#pragma unroll
    for (int r = 0; r < 4; ++r) {
      int row = g * 4 + r;
      float uv = tanh_f(pu[cf][r] + buF[cf]);
      float cj = sigm(pi[cf][r] + biF[cf]) * uv + fca[cf][r];
      float hj = sigm(po[cf][r] + boF[cf]) * tanh_f(cj);
      hbuf[fxsw(row, col)] = cj;  // gemm reads of hbuf retired (program order)
      cbuf[fxsw(row, col)] = hj;
    }
  }

  // coalesced stores (1KB per instr)
  float* outc = out + (size_t)NB * 128;
#pragma unroll
  for (int i = 0; i < 8; ++i) {
    int row = (lane >> 5) + 2 * i;
    f32x4 cj = *(const f32x4*)(hbuf + fxsw(row, c4 * 4));
    f32x4 hj = *(const f32x4*)(cbuf + fxsw(row, c4 * 4));
    *(f32x4*)(outc + (size_t)(row0 + row) * 128 + c4 * 4) = cj;
    *(f32x4*)(out + (size_t)(row0 + row) * 128 + c4 * 4) = hj;
  }
}

extern "C" void kernel_launch(void* const* d_in, const int* in_sizes, int n_in,
                              void* d_out, int out_size, void* d_ws, size_t ws_size,
                              hipStream_t stream) {
  (void)in_sizes; (void)n_in; (void)out_size; (void)d_ws; (void)ws_size;
  const float* x = (const float*)d_in[0];
  const float* h = (const float*)d_in[1];
  const float* C = (const float*)d_in[2];

  prep_weights<<<8, 256, 0, stream>>>(
      (const float*)d_in[3], (const float*)d_in[4], (const float*)d_in[5],
      (const float*)d_in[6], (const float*)d_in[7], (const float*)d_in[8],
      (const float*)d_in[9], (const float*)d_in[10]);

  tree_lstm<<<NB / RPW, 64, 0, stream>>>(
      x, h, C,
      (const float*)d_in[11], (const float*)d_in[12],
      (const float*)d_in[13], (const float*)d_in[14],
      (float*)d_out);
}